// Round 9
// baseline (526.389 us; speedup 1.0000x reference)
//
#include <hip/hip_runtime.h>
#include <hip/hip_fp16.h>

#define OT_B 64
#define OT_N 512
#define OT_M 512
#define OT_ITERS 50
#define OT_STAB 1e-8f
#define OT_NWG 8                    // WGs cooperating per batch
#define OT_ROWS 64                  // rows per slice
#define OT_T 1024
#define NPAIR 32                    // WG n handles batches (n&31) and (n&31)+32
#define KSLICE_U (OT_ROWS * 256)    // uints per K slice (64 rows x 256 half2)
#define DYN_BYTES (2 * KSLICE_U * 4 + 16384)   // 128 KiB K + 16 KiB scratch

// Sinkhorn: 256 WGs (1/CU — validated residency), each WG owns slice g of TWO
// batches and interleaves their phases so each batch's barrier wait is hidden
// behind the other batch's compute. Sync protocol identical to rounds 4/5:
// parity double-buffered partials, relaxed agent atomics, release counter,
// no cache fences.
__global__ __launch_bounds__(OT_T, 4) void ot_sinkhorn_dual(
        const float* __restrict__ Cg,
        float* __restrict__ Pout,
        float* __restrict__ lossOut,
        float* __restrict__ partial,   // [2][B][NWG][M] floats (2 MB)
        int* __restrict__ counters)    // [B][32]
{
    extern __shared__ __align__(16) unsigned char smem[];
    unsigned* __restrict__ Klds = (unsigned*)smem;              // 2 x 64 KiB
    float* __restrict__ scrf = (float*)(smem + 2 * KSLICE_U * 4); // 16 KiB
    float2* __restrict__ scr2 = (float2*)scrf;
    __shared__ float v_lds[2][OT_M];
    __shared__ float u_lds[2][OT_ROWS];

    const int n = blockIdx.x;
    const int g = n >> 5;            // slice 0..7
    const int p = n & 31;            // pair 0..31 (all 8 WGs of a pair: n%8==p%8 -> same XCD heuristic)
    const int t = threadIdx.x;

    const int batA = p, batB = p + NPAIR;
    const size_t offA = ((size_t)batA * OT_N + g * OT_ROWS) * OT_M;
    const size_t offB = ((size_t)batB * OT_N + g * OT_ROWS) * OT_M;
    int* cntA = counters + batA * 32;
    int* cntB = counters + batB * 32;

    // ---- stage both K slices: fp16 exp, uint-swizzled d^(r&31) ----
    {
        const float4* C4A = (const float4*)(Cg + offA);
        const float4* C4B = (const float4*)(Cg + offB);
        #pragma unroll
        for (int s = 0; s < 2; ++s) {
            const float4* C4 = s ? C4B : C4A;
            unsigned* Ks = Klds + s * KSLICE_U;
            #pragma unroll
            for (int ch = 0; ch < 8; ++ch) {
                int idx = ch * OT_T + t;       // 8192 float4 in 64x512 slice
                int r = idx >> 7, c4 = idx & 127;
                float4 c = C4[idx];
                __half2 h0 = __floats2half2_rn(__expf(-20.f * c.x), __expf(-20.f * c.y));
                __half2 h1 = __floats2half2_rn(__expf(-20.f * c.z), __expf(-20.f * c.w));
                int d0 = 2 * c4;
                Ks[r * 256 + ((d0)     ^ (r & 31))] = *(unsigned*)&h0;
                Ks[r * 256 + ((d0 + 1) ^ (r & 31))] = *(unsigned*)&h1;
            }
        }
        if (t < OT_ROWS) { u_lds[0][t] = 1.f / OT_N; u_lds[1][t] = 1.f / OT_N; }
        __syncthreads();
    }

    // ---- phase helpers ----
    auto ph1 = [&](int s, float* buf) {            // partial col sums -> buf[g][:]
        const int d1 = t & 255, q1 = t >> 8;
        const unsigned* Ks = Klds + s * KSLICE_U;
        float2 acc = {0.f, 0.f};
        #pragma unroll
        for (int i = 0; i < 16; ++i) {
            int r = q1 * 16 + i;
            unsigned kk = Ks[r * 256 + (d1 ^ (r & 31))];   // bank-permutation: conflict-free
            float2 f = __half22float2(*(__half2*)&kk);
            float uu = u_lds[s][r];
            acc.x += f.x * uu; acc.y += f.y * uu;
        }
        scr2[t] = acc;
        __syncthreads();
        if (t < 256) {
            float2 a = scr2[t], b2 = scr2[t + 256], c2 = scr2[t + 512], d2 = scr2[t + 768];
            float2 o;
            o.x = a.x + b2.x + c2.x + d2.x;
            o.y = a.y + b2.y + c2.y + d2.y;
            unsigned long long bits;
            __builtin_memcpy(&bits, &o, 8);
            __hip_atomic_store((unsigned long long*)(buf + g * OT_M) + t, bits,
                               __ATOMIC_RELAXED, __HIP_MEMORY_SCOPE_AGENT);
        }
        __syncthreads();    // drains stores (each wave's vmcnt) before arrive
    };
    auto arrive = [&](int* cnt) {
        if (t == 0)
            __hip_atomic_fetch_add(cnt, 1, __ATOMIC_RELEASE, __HIP_MEMORY_SCOPE_AGENT);
    };
    auto waitc = [&](int* cnt, int target) {
        if (t == 0) {
            while (__hip_atomic_load(cnt, __ATOMIC_RELAXED, __HIP_MEMORY_SCOPE_AGENT) < target)
                __builtin_amdgcn_s_sleep(2);
            asm volatile("" ::: "memory");
        }
        __syncthreads();
    };
    auto ph2a = [&](int s, const float* buf) {     // v from the 8 partials
        #pragma unroll
        for (int k = 0; k < 2; ++k) {
            int e = k * OT_T + t;                  // 2048 ull = 8x512 floats
            unsigned long long bits = __hip_atomic_load(
                (const unsigned long long*)buf + e,
                __ATOMIC_RELAXED, __HIP_MEMORY_SCOPE_AGENT);
            float2 f;
            __builtin_memcpy(&f, &bits, 8);
            scr2[e] = f;
        }
        __syncthreads();
        if (t < OT_M) {
            float ssum = OT_STAB;
            #pragma unroll
            for (int w = 0; w < OT_NWG; ++w) ssum += scrf[w * OT_M + t];
            v_lds[s][t] = (1.0f / OT_M) / ssum;
        }
        __syncthreads();
    };
    auto ph2b = [&](int s) {                       // u for own rows (local only)
        const int r2 = t & 63, q2 = t >> 6;
        const unsigned* Ks = Klds + s * KSLICE_U;
        float a2 = 0.f;
        #pragma unroll
        for (int i = 0; i < 16; ++i) {
            int d = q2 * 16 + i;
            unsigned kk = Ks[r2 * 256 + (d ^ (r2 & 31))];  // 2-way bank = free
            float2 f = __half22float2(*(__half2*)&kk);
            float2 vv = ((const float2*)v_lds[s])[d];       // wave-broadcast
            a2 += f.x * vv.x + f.y * vv.y;
        }
        scrf[t] = a2;
        __syncthreads();
        if (t < OT_ROWS) {
            float ssum = 0.f;
            #pragma unroll
            for (int w = 0; w < 16; ++w) ssum += scrf[w * OT_ROWS + t];
            u_lds[s][t] = (1.0f / OT_N) / (ssum + OT_STAB);
        }
        __syncthreads();
    };

    // ---- main loop: interleave the two batches to hide barrier latency ----
    for (int it = 0; it < OT_ITERS; ++it) {
        float* bufA = partial + ((size_t)(it & 1) * OT_B + batA) * (OT_NWG * OT_M);
        float* bufB = partial + ((size_t)(it & 1) * OT_B + batB) * (OT_NWG * OT_M);
        const int tgt = OT_NWG * (it + 1);

        ph1(0, bufA); arrive(cntA);
        ph1(1, bufB); arrive(cntB);
        waitc(cntA, tgt);              // covered by ph1(B)
        ph2a(0, bufA); ph2b(0);
        waitc(cntB, tgt);              // covered by ph2(A)
        ph2a(1, bufB); ph2b(1);
    }

    // ---- final: P = u*K*v and loss, both slices ----
    #pragma unroll
    for (int s = 0; s < 2; ++s) {
        const size_t soff = s ? offB : offA;
        const int sbat = s ? batB : batA;
        const int d1 = t & 255, q1 = t >> 8;
        const float2* C2 = (const float2*)(Cg + soff);
        float2* P2 = (float2*)(Pout + soff);
        const unsigned* Ks = Klds + s * KSLICE_U;
        const float2 vv = ((const float2*)v_lds[s])[d1];
        float lacc = 0.f;
        #pragma unroll
        for (int i = 0; i < 16; ++i) {
            int r = q1 * 16 + i;
            unsigned kk = Ks[r * 256 + (d1 ^ (r & 31))];
            float2 f = __half22float2(*(__half2*)&kk);
            float uu = u_lds[s][r];
            int idx = r * 256 + d1;                // float2 index in slice
            float2 c = C2[idx];
            float2 pv;
            pv.x = uu * f.x * vv.x;
            pv.y = uu * f.y * vv.y;
            P2[idx] = pv;
            lacc += pv.x * c.x + pv.y * c.y;
        }
        __syncthreads();                           // protect scrf reuse
        scrf[t] = lacc;
        __syncthreads();
        #pragma unroll
        for (int sh = OT_T / 2; sh >= 64; sh >>= 1) {
            if (t < sh) scrf[t] += scrf[t + sh];
            __syncthreads();
        }
        if (t < 64) {
            float rs = scrf[t];
            #pragma unroll
            for (int off = 32; off >= 1; off >>= 1) rs += __shfl_xor(rs, off);
            if (t == 0) atomicAdd(&lossOut[sbat], rs);
        }
    }
}

extern "C" void kernel_launch(void* const* d_in, const int* in_sizes, int n_in,
                              void* d_out, int out_size, void* d_ws, size_t ws_size,
                              hipStream_t stream) {
    const float* C = (const float*)d_in[0];
    float* P = (float*)d_out;
    float* loss = (float*)d_out + (size_t)OT_B * OT_N * OT_M;

    size_t off = 0;
    float* partial = (float*)((char*)d_ws + off);
    off += (size_t)2 * OT_B * OT_NWG * OT_M * sizeof(float);   // 2 MB
    int* counters = (int*)((char*)d_ws + off);

    hipMemsetAsync(counters, 0, (size_t)OT_B * 32 * sizeof(int), stream);
    hipMemsetAsync(loss, 0, (size_t)OT_B * sizeof(float), stream);

    hipFuncSetAttribute((const void*)ot_sinkhorn_dual,
                        hipFuncAttributeMaxDynamicSharedMemorySize, DYN_BYTES);

    ot_sinkhorn_dual<<<OT_NWG * NPAIR, OT_T, DYN_BYTES, stream>>>(C, P, loss,
                                                                  partial, counters);
}